// Round 8
// baseline (245.931 us; speedup 1.0000x reference)
//
#include <hip/hip_runtime.h>

typedef unsigned short ushort_t;
typedef unsigned int uint_t;

#define BKT_SHIFT 7            // 128 dst-nodes per bucket
#define BKT_NODES 128
#define NBKT_MAX 800           // >= ceil(100000/128)=782
#define EPB 16384              // edges per block in hist/scatter (512 thr x 32)
#define SCOL_CAP 8192          // LDS col staging in fine_fill (32 KB)
#define GNPB 64                // nodes per block in agg_half
#define SCOLG 2560             // LDS col cache per agg_half block (mean 1600, +24 sigma)
#define MNPB 32                // nodes per block in mlp_only

__device__ __forceinline__ ushort_t f2bf(float f) {
    unsigned u = __float_as_uint(f);
    unsigned r = (u + 0x7FFFu + ((u >> 16) & 1u)) >> 16;   // RNE
    return (ushort_t)r;
}
__device__ __forceinline__ float bflo(uint_t u) { return __uint_as_float(u << 16); }
__device__ __forceinline__ float bfhi(uint_t u) { return __uint_as_float(u & 0xFFFF0000u); }

// ---- x (fp32 [N][32]) -> bf16 split halves [2][N][16] -------------------
__global__ void to_bf16_split(const float4* __restrict__ in, uint_t* __restrict__ out,
                              int N) {
    int i = blockIdx.x * blockDim.x + threadIdx.x;    // one float4 (4 ch) per thread
    int n4 = N * 8;
    if (i < n4) {
        float4 v = in[i];
        int n = i >> 3, i4 = i & 7;
        int half = i4 >> 2;                            // ch 0-15 -> 0, 16-31 -> 1
        uint_t u0 = (uint_t)f2bf(v.x) | ((uint_t)f2bf(v.y) << 16);
        uint_t u1 = (uint_t)f2bf(v.z) | ((uint_t)f2bf(v.w) << 16);
        uint_t* o = out + (size_t)half * N * 8 + (size_t)n * 8 + (i4 & 3) * 2;
        o[0] = u0; o[1] = u1;
    }
}

// ---- ranked bucket sort (no global atomics) -----------------------------

__global__ void histA(const int* __restrict__ dst, int* __restrict__ hist,
                      int E, int NBKT) {
    __shared__ int lcnt[NBKT_MAX];
    int t = threadIdx.x, blk = blockIdx.x;
    for (int b = t; b < NBKT; b += 512) lcnt[b] = 0;
    __syncthreads();
    int e0 = blk * EPB;
    #pragma unroll
    for (int i = 0; i < 32; ++i) {
        int e = e0 + i * 512 + t;
        if (e < E) atomicAdd(&lcnt[dst[e] >> BKT_SHIFT], 1);
    }
    __syncthreads();
    for (int b = t; b < NBKT; b += 512) hist[blk * NBKT + b] = lcnt[b];
}

__global__ void colscan(int* __restrict__ hist, int* __restrict__ T,
                        int NBLK, int NBKT) {
    __shared__ int lds[256];
    int b = blockIdx.x, t = threadIdx.x;
    int j0 = t * 4;
    int v0 = (j0 + 0 < NBLK) ? hist[(j0 + 0) * NBKT + b] : 0;
    int v1 = (j0 + 1 < NBLK) ? hist[(j0 + 1) * NBKT + b] : 0;
    int v2 = (j0 + 2 < NBLK) ? hist[(j0 + 2) * NBKT + b] : 0;
    int v3 = (j0 + 3 < NBLK) ? hist[(j0 + 3) * NBKT + b] : 0;
    lds[t] = v0 + v1 + v2 + v3;
    __syncthreads();
    for (int off = 1; off < 256; off <<= 1) {
        int add = (t >= off) ? lds[t - off] : 0;
        __syncthreads();
        lds[t] += add;
        __syncthreads();
    }
    int p = (t == 0) ? 0 : lds[t - 1];
    if (j0 + 0 < NBLK) hist[(j0 + 0) * NBKT + b] = p;  p += v0;
    if (j0 + 1 < NBLK) hist[(j0 + 1) * NBKT + b] = p;  p += v1;
    if (j0 + 2 < NBLK) hist[(j0 + 2) * NBKT + b] = p;  p += v2;
    if (j0 + 3 < NBLK) hist[(j0 + 3) * NBKT + b] = p;
    if (t == 255) T[b] = lds[255];
}

__global__ void scan_small(const int* __restrict__ in, int* __restrict__ out,
                           int M, int E) {
    __shared__ int lds[1024];
    int t = threadIdx.x;
    int base = t * 4;
    int v0 = (base + 0 < M) ? in[base + 0] : 0;
    int v1 = (base + 1 < M) ? in[base + 1] : 0;
    int v2 = (base + 2 < M) ? in[base + 2] : 0;
    int v3 = (base + 3 < M) ? in[base + 3] : 0;
    lds[t] = v0 + v1 + v2 + v3;
    __syncthreads();
    for (int off = 1; off < 1024; off <<= 1) {
        int add = (t >= off) ? lds[t - off] : 0;
        __syncthreads();
        lds[t] += add;
        __syncthreads();
    }
    int p = (t == 0) ? 0 : lds[t - 1];
    if (base + 0 < M) out[base + 0] = p;  p += v0;
    if (base + 1 < M) out[base + 1] = p;  p += v1;
    if (base + 2 < M) out[base + 2] = p;  p += v2;
    if (base + 3 < M) out[base + 3] = p;
    if (t == 0) out[M] = E;
}

__global__ void scatter_kernel(const int* __restrict__ src, const int* __restrict__ dst,
                               const int* __restrict__ hist, const int* __restrict__ Tscan,
                               int* __restrict__ staged, int E, int NBKT) {
    __shared__ int lbase[NBKT_MAX];
    __shared__ int lcur[NBKT_MAX];
    int t = threadIdx.x, blk = blockIdx.x;
    for (int b = t; b < NBKT; b += 512) {
        lbase[b] = hist[blk * NBKT + b] + Tscan[b];
        lcur[b] = 0;
    }
    __syncthreads();
    int e0 = blk * EPB;
    #pragma unroll
    for (int i = 0; i < 32; ++i) {
        int e = e0 + i * 512 + t;
        if (e < E) {
            int d = dst[e], s = src[e];
            int b = d >> BKT_SHIFT;
            int r = atomicAdd(&lcur[b], 1);
            staged[lbase[b] + r] = ((d & (BKT_NODES - 1)) << 24) | s;
        }
    }
}

__global__ void fine_fill(const int* __restrict__ staged, const int* __restrict__ Tscan,
                          int* __restrict__ rp, int* __restrict__ col,
                          int N, int E, int NBKT) {
    __shared__ int scnt[256];
    __shared__ int srel[256];
    __shared__ int scur[256];
    __shared__ int scol[SCOL_CAP];
    int b = blockIdx.x, t = threadIdx.x;
    int n0 = b << BKT_SHIFT;
    int nn = min(BKT_NODES, N - n0);
    int e0 = Tscan[b];
    int e1 = Tscan[b + 1];
    int m = e1 - e0;

    scnt[t] = 0; scur[t] = 0;
    __syncthreads();
    for (int i = t; i < m; i += 256) {
        int dl = ((unsigned)staged[e0 + i]) >> 24;
        atomicAdd(&scnt[dl], 1);
    }
    __syncthreads();
    int inc_in = scnt[t];
    for (int off = 1; off < 256; off <<= 1) {
        int add = (t >= off) ? scnt[t - off] : 0;
        __syncthreads();
        scnt[t] += add;
        __syncthreads();
    }
    int excl = scnt[t] - inc_in;
    srel[t] = excl;
    if (t < nn) rp[n0 + t] = e0 + excl;
    if (b == NBKT - 1 && t == 0) rp[N] = E;
    __syncthreads();

    if (m <= SCOL_CAP) {
        for (int i = t; i < m; i += 256) {
            int v = staged[e0 + i];
            int dl = ((unsigned)v) >> 24;
            int p = srel[dl] + atomicAdd(&scur[dl], 1);
            scol[p] = v & 0xFFFFFF;
        }
        __syncthreads();
        for (int i = t; i < m; i += 256) col[e0 + i] = scol[i];
    } else {
        for (int i = t; i < m; i += 256) {
            int v = staged[e0 + i];
            int dl = ((unsigned)v) >> 24;
            int p = srel[dl] + atomicAdd(&scur[dl], 1);
            col[e0 + p] = v & 0xFFFFFF;
        }
    }
}

// ---- gather one channel-half (L2-resident: 3.2 MB half-row array) -------
// Block = 256 thr = 64 nodes x 4 lanes (uint2 = 4 bf16 ch per lane).
// One wave-inst gathers 16 rows (16 edges). col prefetched to LDS.
__global__ void agg_half(const uint_t* __restrict__ xh,   // [N][8] uints
                         const int* __restrict__ rp, const int* __restrict__ col,
                         float4* __restrict__ vh, int N) { // [N][16] fp32 (as float4[N*4])
    __shared__ int scol[SCOLG];
    int t = threadIdx.x;
    int base = blockIdx.x * GNPB;
    int nend = min(base + GNPB, N);
    int kb = rp[base], kt = rp[nend];
    int tot = kt - kb;
    bool ovf = (tot > SCOLG);
    if (!ovf) {
        for (int i = t; i < tot; i += 256) scol[i] = col[kb + i];
    }
    __syncthreads();

    int ln = t >> 2, sl = t & 3;       // node slot 0..63, uint2 slot 0..3
    int n = base + ln;
    if (n >= N) return;
    const uint2* x2 = (const uint2*)xh;
    uint2 us = x2[(size_t)n * 4 + sl];
    float v0 = bflo(us.x), v1 = bfhi(us.x), v2 = bflo(us.y), v3 = bfhi(us.y);
    int ks = rp[n], ke = rp[n + 1];
    if (!ovf) {
        int k = ks - kb, kend = ke - kb;
        for (; k + 8 <= kend; k += 8) {
            int s0 = scol[k + 0], s1 = scol[k + 1], s2 = scol[k + 2], s3 = scol[k + 3];
            int s4 = scol[k + 4], s5 = scol[k + 5], s6 = scol[k + 6], s7 = scol[k + 7];
            uint2 u0 = x2[(size_t)s0 * 4 + sl];
            uint2 u1 = x2[(size_t)s1 * 4 + sl];
            uint2 u2 = x2[(size_t)s2 * 4 + sl];
            uint2 u3 = x2[(size_t)s3 * 4 + sl];
            uint2 u4 = x2[(size_t)s4 * 4 + sl];
            uint2 u5 = x2[(size_t)s5 * 4 + sl];
            uint2 u6 = x2[(size_t)s6 * 4 + sl];
            uint2 u7 = x2[(size_t)s7 * 4 + sl];
            v0 += ((bflo(u0.x) + bflo(u1.x)) + (bflo(u2.x) + bflo(u3.x)))
                + ((bflo(u4.x) + bflo(u5.x)) + (bflo(u6.x) + bflo(u7.x)));
            v1 += ((bfhi(u0.x) + bfhi(u1.x)) + (bfhi(u2.x) + bfhi(u3.x)))
                + ((bfhi(u4.x) + bfhi(u5.x)) + (bfhi(u6.x) + bfhi(u7.x)));
            v2 += ((bflo(u0.y) + bflo(u1.y)) + (bflo(u2.y) + bflo(u3.y)))
                + ((bflo(u4.y) + bflo(u5.y)) + (bflo(u6.y) + bflo(u7.y)));
            v3 += ((bfhi(u0.y) + bfhi(u1.y)) + (bfhi(u2.y) + bfhi(u3.y)))
                + ((bfhi(u4.y) + bfhi(u5.y)) + (bfhi(u6.y) + bfhi(u7.y)));
        }
        for (; k < kend; ++k) {
            uint2 u = x2[(size_t)scol[k] * 4 + sl];
            v0 += bflo(u.x); v1 += bfhi(u.x); v2 += bflo(u.y); v3 += bfhi(u.y);
        }
    } else {  // statistically unreachable
        for (int k = ks; k < ke; ++k) {
            uint2 u = x2[(size_t)col[k] * 4 + sl];
            v0 += bflo(u.x); v1 += bfhi(u.x); v2 += bflo(u.y); v3 += bfhi(u.y);
        }
    }
    float4 o; o.x = v0; o.y = v1; o.z = v2; o.w = v3;
    vh[(size_t)n * 4 + sl] = o;
}

// ---- MLP over assembled v ----------------------------------------------
// Block = 256 thr = 32 nodes x 8 lanes. Lane: load float4 (4 ch), compute 2
// hidden units, then 4 out channels. bf16 halves out (conv1) or fp32 (final).
template <bool RELU_OUT, bool OUT_BF16>
__global__ void mlp_only(const float4* __restrict__ v0h, const float4* __restrict__ v1h,
                         const float* __restrict__ Wa, const float* __restrict__ ba,
                         const float* __restrict__ Wb, const float* __restrict__ bb,
                         void* __restrict__ outv, int N) {
    __shared__ float sWa[32 * 16];
    __shared__ float sWb[16 * 32];
    __shared__ float sba[16], sbb[32];
    __shared__ float sv[MNPB][33];
    __shared__ float st1[MNPB][17];

    int t = threadIdx.x;
    sWa[t] = Wa[t];  sWa[t + 256] = Wa[t + 256];
    sWb[t] = Wb[t];  sWb[t + 256] = Wb[t + 256];
    if (t < 16) sba[t] = ba[t];
    if (t < 32) sbb[t] = bb[t];

    int ln = t >> 3, sl = t & 7;
    int n = blockIdx.x * MNPB + ln;
    bool act = (n < N);
    if (act) {
        float4 v = (sl < 4) ? v0h[(size_t)n * 4 + sl] : v1h[(size_t)n * 4 + (sl - 4)];
        int c0 = sl * 4;
        sv[ln][c0 + 0] = v.x; sv[ln][c0 + 1] = v.y;
        sv[ln][c0 + 2] = v.z; sv[ln][c0 + 3] = v.w;
    }
    __syncthreads();

    if (act) {                       // hidden units sl and sl+8
        float ha = sba[sl], hb = sba[sl + 8];
        #pragma unroll
        for (int cc = 0; cc < 32; ++cc) {
            float vc = sv[ln][cc];
            ha += vc * sWa[cc * 16 + sl];
            hb += vc * sWa[cc * 16 + sl + 8];
        }
        st1[ln][sl]     = fmaxf(ha, 0.f);
        st1[ln][sl + 8] = fmaxf(hb, 0.f);
    }
    __syncthreads();

    if (act) {                       // out channels sl*4 .. sl*4+3
        int c0 = sl * 4;
        float a0 = sbb[c0], a1 = sbb[c0 + 1], a2 = sbb[c0 + 2], a3 = sbb[c0 + 3];
        #pragma unroll
        for (int j = 0; j < 16; ++j) {
            float hj = st1[ln][j];
            a0 += hj * sWb[j * 32 + c0];
            a1 += hj * sWb[j * 32 + c0 + 1];
            a2 += hj * sWb[j * 32 + c0 + 2];
            a3 += hj * sWb[j * 32 + c0 + 3];
        }
        if (RELU_OUT) {
            a0 = fmaxf(a0, 0.f); a1 = fmaxf(a1, 0.f);
            a2 = fmaxf(a2, 0.f); a3 = fmaxf(a3, 0.f);
        }
        if (OUT_BF16) {              // [2][N][16] bf16 halves
            uint2 p;
            p.x = (uint_t)f2bf(a0) | ((uint_t)f2bf(a1) << 16);
            p.y = (uint_t)f2bf(a2) | ((uint_t)f2bf(a3) << 16);
            uint2* o = (uint2*)outv;
            size_t halfoff = (sl >= 4) ? (size_t)N * 4 : 0;
            o[halfoff + (size_t)n * 4 + (sl & 3)] = p;
        } else {                     // fp32 [N][32]
            float4 o4; o4.x = a0; o4.y = a1; o4.z = a2; o4.w = a3;
            ((float4*)outv)[(size_t)n * 8 + sl] = o4;
        }
    }
}

// ---- Launch -------------------------------------------------------------

extern "C" void kernel_launch(void* const* d_in, const int* in_sizes, int n_in,
                              void* d_out, int out_size, void* d_ws, size_t ws_size,
                              hipStream_t stream) {
    const float* x  = (const float*)d_in[0];
    const int*   ei = (const int*)d_in[1];
    const float* W1 = (const float*)d_in[2];
    const float* b1 = (const float*)d_in[3];
    const float* W2 = (const float*)d_in[4];
    const float* b2 = (const float*)d_in[5];
    const float* W3 = (const float*)d_in[6];
    const float* b3 = (const float*)d_in[7];
    const float* W4 = (const float*)d_in[8];
    const float* b4 = (const float*)d_in[9];

    const int N = in_sizes[0] / 32;
    const int E = in_sizes[1] / 2;
    const int* src = ei;
    const int* dst = ei + E;

    const int NBKT = (N + BKT_NODES - 1) >> BKT_SHIFT;   // 782
    const int NBLK = (E + EPB - 1) / EPB;                // 153

    char* ws = (char*)d_ws;
    size_t o = 0;
    auto alloc = [&](size_t bytes) -> char* {
        o = (o + 255) & ~(size_t)255;
        char* r = ws + o;
        o += bytes;
        return r;
    };
    int*    hist   = (int*)   alloc(4 * (size_t)NBLK * NBKT);
    int*    T      = (int*)   alloc(4 * (size_t)NBKT);
    int*    Tscan  = (int*)   alloc(4 * (size_t)(NBKT + 1));
    int*    staged = (int*)   alloc(4 * (size_t)E);
    int*    rp     = (int*)   alloc(4 * (size_t)(N + 1));
    int*    col    = (int*)   alloc(4 * (size_t)E);
    uint_t* xb     = (uint_t*)alloc(2 * (size_t)N * 32);   // [2][N][8] uints
    uint_t* hb     = (uint_t*)alloc(2 * (size_t)N * 32);   // [2][N][8] uints
    float*  vv     = (float*) alloc(4 * (size_t)N * 32);   // [2][N][16] fp32

    float4* vv0 = (float4*)vv;
    float4* vv1 = (float4*)(vv + (size_t)N * 16);

    int n4 = N * 8;
    to_bf16_split<<<(n4 + 255) / 256, 256, 0, stream>>>((const float4*)x, xb, N);

    histA<<<NBLK, 512, 0, stream>>>(dst, hist, E, NBKT);
    colscan<<<NBKT, 256, 0, stream>>>(hist, T, NBLK, NBKT);
    scan_small<<<1, 1024, 0, stream>>>(T, Tscan, NBKT, E);
    scatter_kernel<<<NBLK, 512, 0, stream>>>(src, dst, hist, Tscan, staged, E, NBKT);
    fine_fill<<<NBKT, 256, 0, stream>>>(staged, Tscan, rp, col, N, E, NBKT);

    int gagg = (N + GNPB - 1) / GNPB;
    int gmlp = (N + MNPB - 1) / MNPB;

    // conv1
    agg_half<<<gagg, 256, 0, stream>>>(xb,              rp, col, vv0, N);
    agg_half<<<gagg, 256, 0, stream>>>(xb + (size_t)N * 8, rp, col, vv1, N);
    mlp_only<true,  true ><<<gmlp, 256, 0, stream>>>(vv0, vv1, W1, b1, W2, b2, hb, N);
    // conv2
    agg_half<<<gagg, 256, 0, stream>>>(hb,              rp, col, vv0, N);
    agg_half<<<gagg, 256, 0, stream>>>(hb + (size_t)N * 8, rp, col, vv1, N);
    mlp_only<false, false><<<gmlp, 256, 0, stream>>>(vv0, vv1, W3, b3, W4, b4, d_out, N);
}

// Round 9
// 212.962 us; speedup vs baseline: 1.1548x; 1.1548x over previous
//
#include <hip/hip_runtime.h>

typedef unsigned short ushort_t;
typedef unsigned int uint_t;

#define BKT_SHIFT 8            // 256 dst-nodes per bucket
#define BKT_NODES 256
#define NBKT_MAX 400           // >= ceil(100000/256)=391
#define EPB 8192               // edges per block in hist/scatter (512 thr x 16)
#define SCOL_CAP 8192          // LDS col staging in fine_fill (32 KB); mean bucket = 6400
#define NPB 16                 // nodes per block in agg_mlp
#define SCOL_N 768             // LDS col cache per agg block (mean 400, +18 sigma)

__device__ __forceinline__ ushort_t f2bf(float f) {
    unsigned u = __float_as_uint(f);
    unsigned r = (u + 0x7FFFu + ((u >> 16) & 1u)) >> 16;   // RNE
    return (ushort_t)r;
}

// ---- x -> bf16 ----------------------------------------------------------
__global__ void to_bf16(const float4* __restrict__ in, ushort_t* __restrict__ out, int n4) {
    int i = blockIdx.x * blockDim.x + threadIdx.x;
    if (i < n4) {
        float4 v = in[i];
        out[i * 4 + 0] = f2bf(v.x);
        out[i * 4 + 1] = f2bf(v.y);
        out[i * 4 + 2] = f2bf(v.z);
        out[i * 4 + 3] = f2bf(v.w);
    }
}

// ---- ranked bucket sort (no global atomics) -----------------------------

__global__ void histA(const int* __restrict__ dst, int* __restrict__ hist,
                      int E, int NBKT) {
    __shared__ int lcnt[NBKT_MAX];
    int t = threadIdx.x, blk = blockIdx.x;
    for (int b = t; b < NBKT; b += 512) lcnt[b] = 0;
    __syncthreads();
    int e0 = blk * EPB;
    #pragma unroll
    for (int i = 0; i < 16; ++i) {
        int e = e0 + i * 512 + t;
        if (e < E) atomicAdd(&lcnt[dst[e] >> BKT_SHIFT], 1);
    }
    __syncthreads();
    for (int b = t; b < NBKT; b += 512) hist[blk * NBKT + b] = lcnt[b];
}

// One block per bucket: exclusive scan of hist column b over NBLK blocks
// (in place), total -> T[b]. NBLK <= 1024 (256 thr x 4).
__global__ void colscan(int* __restrict__ hist, int* __restrict__ T,
                        int NBLK, int NBKT) {
    __shared__ int lds[256];
    int b = blockIdx.x, t = threadIdx.x;
    int j0 = t * 4;
    int v0 = (j0 + 0 < NBLK) ? hist[(j0 + 0) * NBKT + b] : 0;
    int v1 = (j0 + 1 < NBLK) ? hist[(j0 + 1) * NBKT + b] : 0;
    int v2 = (j0 + 2 < NBLK) ? hist[(j0 + 2) * NBKT + b] : 0;
    int v3 = (j0 + 3 < NBLK) ? hist[(j0 + 3) * NBKT + b] : 0;
    lds[t] = v0 + v1 + v2 + v3;
    __syncthreads();
    for (int off = 1; off < 256; off <<= 1) {
        int add = (t >= off) ? lds[t - off] : 0;
        __syncthreads();
        lds[t] += add;
        __syncthreads();
    }
    int p = (t == 0) ? 0 : lds[t - 1];
    if (j0 + 0 < NBLK) hist[(j0 + 0) * NBKT + b] = p;  p += v0;
    if (j0 + 1 < NBLK) hist[(j0 + 1) * NBKT + b] = p;  p += v1;
    if (j0 + 2 < NBLK) hist[(j0 + 2) * NBKT + b] = p;  p += v2;
    if (j0 + 3 < NBLK) hist[(j0 + 3) * NBKT + b] = p;
    if (t == 255) T[b] = lds[255];
}

// Single block: exclusive scan of M (<=4096) ints, out[M] = E.
__global__ void scan_small(const int* __restrict__ in, int* __restrict__ out,
                           int M, int E) {
    __shared__ int lds[1024];
    int t = threadIdx.x;
    int base = t * 4;
    int v0 = (base + 0 < M) ? in[base + 0] : 0;
    int v1 = (base + 1 < M) ? in[base + 1] : 0;
    int v2 = (base + 2 < M) ? in[base + 2] : 0;
    int v3 = (base + 3 < M) ? in[base + 3] : 0;
    lds[t] = v0 + v1 + v2 + v3;
    __syncthreads();
    for (int off = 1; off < 1024; off <<= 1) {
        int add = (t >= off) ? lds[t - off] : 0;
        __syncthreads();
        lds[t] += add;
        __syncthreads();
    }
    int p = (t == 0) ? 0 : lds[t - 1];
    if (base + 0 < M) out[base + 0] = p;  p += v0;
    if (base + 1 < M) out[base + 1] = p;  p += v1;
    if (base + 2 < M) out[base + 2] = p;  p += v2;
    if (base + 3 < M) out[base + 3] = p;
    if (t == 0) out[M] = E;
}

// Rank via LDS atomics; write packed (dl<<24)|src into bucket runs
// (~21 consecutive slots per (block,bucket) => line-coalesced scatter).
__global__ void scatter_kernel(const int* __restrict__ src, const int* __restrict__ dst,
                               const int* __restrict__ hist, const int* __restrict__ Tscan,
                               int* __restrict__ staged, int E, int NBKT) {
    __shared__ int lbase[NBKT_MAX];
    __shared__ int lcur[NBKT_MAX];
    int t = threadIdx.x, blk = blockIdx.x;
    for (int b = t; b < NBKT; b += 512) {
        lbase[b] = hist[blk * NBKT + b] + Tscan[b];
        lcur[b] = 0;
    }
    __syncthreads();
    int e0 = blk * EPB;
    #pragma unroll
    for (int i = 0; i < 16; ++i) {
        int e = e0 + i * 512 + t;
        if (e < E) {
            int d = dst[e], s = src[e];
            int b = d >> BKT_SHIFT;
            int r = atomicAdd(&lcur[b], 1);
            staged[lbase[b] + r] = ((d & (BKT_NODES - 1)) << 24) | s;
        }
    }
}

// One block per bucket: LDS per-node count -> scan (writes rp!) -> LDS place
// -> coalesced col flush.
__global__ void fine_fill(const int* __restrict__ staged, const int* __restrict__ Tscan,
                          int* __restrict__ rp, int* __restrict__ col,
                          int N, int E, int NBKT) {
    __shared__ int scnt[256];
    __shared__ int srel[256];
    __shared__ int scur[256];
    __shared__ int scol[SCOL_CAP];
    int b = blockIdx.x, t = threadIdx.x;
    int n0 = b << BKT_SHIFT;
    int nn = min(BKT_NODES, N - n0);
    int e0 = Tscan[b];
    int e1 = Tscan[b + 1];
    int m = e1 - e0;

    scnt[t] = 0; scur[t] = 0;
    __syncthreads();
    for (int i = t; i < m; i += 256) {
        int dl = ((unsigned)staged[e0 + i]) >> 24;
        atomicAdd(&scnt[dl], 1);
    }
    __syncthreads();
    int inc_in = scnt[t];
    for (int off = 1; off < 256; off <<= 1) {   // Hillis-Steele inclusive
        int add = (t >= off) ? scnt[t - off] : 0;
        __syncthreads();
        scnt[t] += add;
        __syncthreads();
    }
    int excl = scnt[t] - inc_in;
    srel[t] = excl;
    if (t < nn) rp[n0 + t] = e0 + excl;
    if (b == NBKT - 1 && t == 0) rp[N] = E;
    __syncthreads();

    if (m <= SCOL_CAP) {
        for (int i = t; i < m; i += 256) {
            int v = staged[e0 + i];
            int dl = ((unsigned)v) >> 24;
            int p = srel[dl] + atomicAdd(&scur[dl], 1);
            scol[p] = v & 0xFFFFFF;
        }
        __syncthreads();
        for (int i = t; i < m; i += 256) col[e0 + i] = scol[i];
    } else {  // statistically unreachable overflow fallback
        for (int i = t; i < m; i += 256) {
            int v = staged[e0 + i];
            int dl = ((unsigned)v) >> 24;
            int p = srel[dl] + atomicAdd(&scur[dl], 1);
            col[e0 + p] = v & 0xFFFFFF;
        }
    }
}

// ---- Fused aggregate + MLP (R7 structure) -------------------------------
// Block = 256 threads = 16 nodes x 16 lanes; each lane handles 2 channels via
// packed-bf16 uint loads => one gather instruction serves 4 edges (4 nodes/wave).
// col prefetched to LDS with NONTEMPORAL loads; outputs stored nontemporal —
// keeps the per-XCD L2 reserved for x-row reuse (R7 hit rate was only ~50%).

template <bool RELU_OUT, bool OUT_BF16>
__global__ void agg_mlp(const ushort_t* __restrict__ xin, const int* __restrict__ rp,
                        const int* __restrict__ col,
                        const float* __restrict__ Wa, const float* __restrict__ ba,
                        const float* __restrict__ Wb, const float* __restrict__ bb,
                        void* __restrict__ outv, int N) {
    __shared__ float sWa[32 * 16];
    __shared__ float sWb[16 * 32];
    __shared__ float sba[16], sbb[32];
    __shared__ float sv[NPB][32];
    __shared__ float st1[NPB][16];
    __shared__ int scol[SCOL_N];

    int t = threadIdx.x;
    sWa[t] = Wa[t];  sWa[t + 256] = Wa[t + 256];
    sWb[t] = Wb[t];  sWb[t + 256] = Wb[t + 256];
    if (t < 16) sba[t] = ba[t];
    if (t < 32) sbb[t] = bb[t];

    int base = blockIdx.x * NPB;
    int kb = rp[base];
    int kt = rp[min(base + NPB, N)];
    int tot = kt - kb;
    bool ovf = (tot > SCOL_N);
    if (!ovf) {
        for (int i = t; i < tot; i += 256)
            scol[i] = __builtin_nontemporal_load(col + kb + i);
    }
    __syncthreads();

    int ln = t >> 4;          // node slot 0..15
    int sl = t & 15;          // channels 2*sl, 2*sl+1
    int n  = base + ln;
    bool act = (n < N);
    const uint_t* x32 = (const uint_t*)xin;   // row = 16 uints (32 bf16)

    if (act) {
        uint_t us = x32[(size_t)n * 16 + sl];
        float vx = __uint_as_float(us << 16);
        float vy = __uint_as_float(us & 0xFFFF0000u);
        int ks = rp[n], ke = rp[n + 1];
        if (!ovf) {
            int k = ks - kb, kend = ke - kb;
            for (; k + 8 <= kend; k += 8) {
                int s0 = scol[k + 0], s1 = scol[k + 1], s2 = scol[k + 2], s3 = scol[k + 3];
                int s4 = scol[k + 4], s5 = scol[k + 5], s6 = scol[k + 6], s7 = scol[k + 7];
                uint_t u0 = x32[(size_t)s0 * 16 + sl];
                uint_t u1 = x32[(size_t)s1 * 16 + sl];
                uint_t u2 = x32[(size_t)s2 * 16 + sl];
                uint_t u3 = x32[(size_t)s3 * 16 + sl];
                uint_t u4 = x32[(size_t)s4 * 16 + sl];
                uint_t u5 = x32[(size_t)s5 * 16 + sl];
                uint_t u6 = x32[(size_t)s6 * 16 + sl];
                uint_t u7 = x32[(size_t)s7 * 16 + sl];
                vx += ((__uint_as_float(u0 << 16) + __uint_as_float(u1 << 16))
                     + (__uint_as_float(u2 << 16) + __uint_as_float(u3 << 16)))
                    + ((__uint_as_float(u4 << 16) + __uint_as_float(u5 << 16))
                     + (__uint_as_float(u6 << 16) + __uint_as_float(u7 << 16)));
                vy += ((__uint_as_float(u0 & 0xFFFF0000u) + __uint_as_float(u1 & 0xFFFF0000u))
                     + (__uint_as_float(u2 & 0xFFFF0000u) + __uint_as_float(u3 & 0xFFFF0000u)))
                    + ((__uint_as_float(u4 & 0xFFFF0000u) + __uint_as_float(u5 & 0xFFFF0000u))
                     + (__uint_as_float(u6 & 0xFFFF0000u) + __uint_as_float(u7 & 0xFFFF0000u)));
            }
            for (; k < kend; ++k) {
                uint_t u0 = x32[(size_t)scol[k] * 16 + sl];
                vx += __uint_as_float(u0 << 16);
                vy += __uint_as_float(u0 & 0xFFFF0000u);
            }
        } else {  // statistically unreachable
            for (int k = ks; k < ke; ++k) {
                uint_t u0 = x32[(size_t)col[k] * 16 + sl];
                vx += __uint_as_float(u0 << 16);
                vy += __uint_as_float(u0 & 0xFFFF0000u);
            }
        }
        sv[ln][2 * sl]     = vx;
        sv[ln][2 * sl + 1] = vy;
    }
    __syncthreads();

    if (act) {   // hidden unit sl for node ln
        float h = sba[sl];
        #pragma unroll
        for (int cc = 0; cc < 32; ++cc) h += sv[ln][cc] * sWa[cc * 16 + sl];
        st1[ln][sl] = fmaxf(h, 0.f);
    }
    __syncthreads();

    if (act) {   // out channels 2*sl, 2*sl+1 for node ln
        int c0 = 2 * sl;
        float a0 = sbb[c0], a1 = sbb[c0 + 1];
        #pragma unroll
        for (int j = 0; j < 16; ++j) {
            float hj = st1[ln][j];
            a0 += hj * sWb[j * 32 + c0];
            a1 += hj * sWb[j * 32 + c0 + 1];
        }
        if (RELU_OUT) { a0 = fmaxf(a0, 0.f); a1 = fmaxf(a1, 0.f); }
        if (OUT_BF16) {
            uint_t p = (uint_t)f2bf(a0) | ((uint_t)f2bf(a1) << 16);
            __builtin_nontemporal_store(p, (uint_t*)outv + (size_t)n * 16 + sl);
        } else {
            float* o = (float*)outv + (size_t)n * 32 + 2 * sl;
            __builtin_nontemporal_store(a0, o);
            __builtin_nontemporal_store(a1, o + 1);
        }
    }
}

// ---- Launch -------------------------------------------------------------

extern "C" void kernel_launch(void* const* d_in, const int* in_sizes, int n_in,
                              void* d_out, int out_size, void* d_ws, size_t ws_size,
                              hipStream_t stream) {
    const float* x  = (const float*)d_in[0];
    const int*   ei = (const int*)d_in[1];
    const float* W1 = (const float*)d_in[2];
    const float* b1 = (const float*)d_in[3];
    const float* W2 = (const float*)d_in[4];
    const float* b2 = (const float*)d_in[5];
    const float* W3 = (const float*)d_in[6];
    const float* b3 = (const float*)d_in[7];
    const float* W4 = (const float*)d_in[8];
    const float* b4 = (const float*)d_in[9];

    const int N = in_sizes[0] / 32;
    const int E = in_sizes[1] / 2;
    const int* src = ei;
    const int* dst = ei + E;

    const int NBKT = (N + BKT_NODES - 1) >> BKT_SHIFT;   // 391
    const int NBLK = (E + EPB - 1) / EPB;                // 306 (<=1024 for colscan)

    char* ws = (char*)d_ws;
    size_t o = 0;
    auto alloc = [&](size_t bytes) -> char* {
        o = (o + 255) & ~(size_t)255;
        char* r = ws + o;
        o += bytes;
        return r;
    };
    int*      hist   = (int*)     alloc(4 * (size_t)NBLK * NBKT);
    int*      T      = (int*)     alloc(4 * (size_t)NBKT);
    int*      Tscan  = (int*)     alloc(4 * (size_t)(NBKT + 1));
    int*      staged = (int*)     alloc(4 * (size_t)E);
    int*      rp     = (int*)     alloc(4 * (size_t)(N + 1));
    int*      col    = (int*)     alloc(4 * (size_t)E);
    ushort_t* xb     = (ushort_t*)alloc(2 * (size_t)N * 32);
    ushort_t* hb     = (ushort_t*)alloc(2 * (size_t)N * 32);

    int n4 = N * 32 / 4;
    to_bf16<<<(n4 + 255) / 256, 256, 0, stream>>>((const float4*)x, xb, n4);

    histA<<<NBLK, 512, 0, stream>>>(dst, hist, E, NBKT);
    colscan<<<NBKT, 256, 0, stream>>>(hist, T, NBLK, NBKT);
    scan_small<<<1, 1024, 0, stream>>>(T, Tscan, NBKT, E);
    scatter_kernel<<<NBLK, 512, 0, stream>>>(src, dst, hist, Tscan, staged, E, NBKT);
    fine_fill<<<NBKT, 256, 0, stream>>>(staged, Tscan, rp, col, N, E, NBKT);

    agg_mlp<true,  true ><<<(N + NPB - 1) / NPB, 256, 0, stream>>>(xb, rp, col,
                                                                   W1, b1, W2, b2, hb, N);
    agg_mlp<false, false><<<(N + NPB - 1) / NPB, 256, 0, stream>>>(hb, rp, col,
                                                                   W3, b3, W4, b4, d_out, N);
}

// Round 11
// 205.980 us; speedup vs baseline: 1.1940x; 1.0339x over previous
//
#include <hip/hip_runtime.h>

typedef unsigned short ushort_t;
typedef unsigned int uint_t;

#define BKT_SHIFT 8            // 256 dst-nodes per bucket
#define BKT_NODES 256
#define NBKT_MAX 400           // >= ceil(100000/256)=391
#define EPB 8192               // edges per block in hist/scatter (512 thr x 16)
#define SCOL_CAP 8192          // LDS col staging in fine_fill (32 KB); mean bucket = 6400
#define NPB 32                 // nodes per block in agg_mlp
#define SCOL_N 1536            // LDS col cache per agg block (mean 800, +26 sigma)

__device__ __forceinline__ ushort_t f2bf(float f) {
    unsigned u = __float_as_uint(f);
    unsigned r = (u + 0x7FFFu + ((u >> 16) & 1u)) >> 16;   // RNE
    return (ushort_t)r;
}
__device__ __forceinline__ float bflo(uint_t u) { return __uint_as_float(u << 16); }
__device__ __forceinline__ float bfhi(uint_t u) { return __uint_as_float(u & 0xFFFF0000u); }

// ---- x -> bf16 ----------------------------------------------------------
__global__ void to_bf16(const float4* __restrict__ in, ushort_t* __restrict__ out, int n4) {
    int i = blockIdx.x * blockDim.x + threadIdx.x;
    if (i < n4) {
        float4 v = in[i];
        out[i * 4 + 0] = f2bf(v.x);
        out[i * 4 + 1] = f2bf(v.y);
        out[i * 4 + 2] = f2bf(v.z);
        out[i * 4 + 3] = f2bf(v.w);
    }
}

// ---- ranked bucket sort (no global atomics) -----------------------------

__global__ void histA(const int* __restrict__ dst, int* __restrict__ hist,
                      int E, int NBKT) {
    __shared__ int lcnt[NBKT_MAX];
    int t = threadIdx.x, blk = blockIdx.x;
    for (int b = t; b < NBKT; b += 512) lcnt[b] = 0;
    __syncthreads();
    int e0 = blk * EPB;
    #pragma unroll
    for (int i = 0; i < 16; ++i) {
        int e = e0 + i * 512 + t;
        if (e < E) atomicAdd(&lcnt[dst[e] >> BKT_SHIFT], 1);
    }
    __syncthreads();
    for (int b = t; b < NBKT; b += 512) hist[blk * NBKT + b] = lcnt[b];
}

__global__ void colscan(int* __restrict__ hist, int* __restrict__ T,
                        int NBLK, int NBKT) {
    __shared__ int lds[256];
    int b = blockIdx.x, t = threadIdx.x;
    int j0 = t * 4;
    int v0 = (j0 + 0 < NBLK) ? hist[(j0 + 0) * NBKT + b] : 0;
    int v1 = (j0 + 1 < NBLK) ? hist[(j0 + 1) * NBKT + b] : 0;
    int v2 = (j0 + 2 < NBLK) ? hist[(j0 + 2) * NBKT + b] : 0;
    int v3 = (j0 + 3 < NBLK) ? hist[(j0 + 3) * NBKT + b] : 0;
    lds[t] = v0 + v1 + v2 + v3;
    __syncthreads();
    for (int off = 1; off < 256; off <<= 1) {
        int add = (t >= off) ? lds[t - off] : 0;
        __syncthreads();
        lds[t] += add;
        __syncthreads();
    }
    int p = (t == 0) ? 0 : lds[t - 1];
    if (j0 + 0 < NBLK) hist[(j0 + 0) * NBKT + b] = p;  p += v0;
    if (j0 + 1 < NBLK) hist[(j0 + 1) * NBKT + b] = p;  p += v1;
    if (j0 + 2 < NBLK) hist[(j0 + 2) * NBKT + b] = p;  p += v2;
    if (j0 + 3 < NBLK) hist[(j0 + 3) * NBKT + b] = p;
    if (t == 255) T[b] = lds[255];
}

__global__ void scan_small(const int* __restrict__ in, int* __restrict__ out,
                           int M, int E) {
    __shared__ int lds[1024];
    int t = threadIdx.x;
    int base = t * 4;
    int v0 = (base + 0 < M) ? in[base + 0] : 0;
    int v1 = (base + 1 < M) ? in[base + 1] : 0;
    int v2 = (base + 2 < M) ? in[base + 2] : 0;
    int v3 = (base + 3 < M) ? in[base + 3] : 0;
    lds[t] = v0 + v1 + v2 + v3;
    __syncthreads();
    for (int off = 1; off < 1024; off <<= 1) {
        int add = (t >= off) ? lds[t - off] : 0;
        __syncthreads();
        lds[t] += add;
        __syncthreads();
    }
    int p = (t == 0) ? 0 : lds[t - 1];
    if (base + 0 < M) out[base + 0] = p;  p += v0;
    if (base + 1 < M) out[base + 1] = p;  p += v1;
    if (base + 2 < M) out[base + 2] = p;  p += v2;
    if (base + 3 < M) out[base + 3] = p;
    if (t == 0) out[M] = E;
}

__global__ void scatter_kernel(const int* __restrict__ src, const int* __restrict__ dst,
                               const int* __restrict__ hist, const int* __restrict__ Tscan,
                               int* __restrict__ staged, int E, int NBKT) {
    __shared__ int lbase[NBKT_MAX];
    __shared__ int lcur[NBKT_MAX];
    int t = threadIdx.x, blk = blockIdx.x;
    for (int b = t; b < NBKT; b += 512) {
        lbase[b] = hist[blk * NBKT + b] + Tscan[b];
        lcur[b] = 0;
    }
    __syncthreads();
    int e0 = blk * EPB;
    #pragma unroll
    for (int i = 0; i < 16; ++i) {
        int e = e0 + i * 512 + t;
        if (e < E) {
            int d = dst[e], s = src[e];
            int b = d >> BKT_SHIFT;
            int r = atomicAdd(&lcur[b], 1);
            staged[lbase[b] + r] = ((d & (BKT_NODES - 1)) << 24) | s;
        }
    }
}

// One block per bucket: per-(node, src-quartile) LDS count -> 1024-wide scan
// (writes rp!) -> LDS place -> coalesced col flush. The quartile sub-sort
// makes agg sweep src in 1.6 MB phases => per-XCD-L2-resident gather set.
__global__ void fine_fill(const int* __restrict__ staged, const int* __restrict__ Tscan,
                          int* __restrict__ rp, int* __restrict__ col,
                          int N, int E, int NBKT, int q1, int q2, int q3) {
    __shared__ int scnt[1024];   // [node][quartile]
    __shared__ int srel[1024];
    __shared__ int scur[1024];
    __shared__ int swsum[256];
    __shared__ int scol[SCOL_CAP];
    int b = blockIdx.x, t = threadIdx.x;
    int n0 = b << BKT_SHIFT;
    int nn = min(BKT_NODES, N - n0);
    int e0 = Tscan[b];
    int e1 = Tscan[b + 1];
    int m = e1 - e0;

    #pragma unroll
    for (int j = 0; j < 4; ++j) { scnt[t * 4 + j] = 0; scur[t * 4 + j] = 0; }
    __syncthreads();
    for (int i = t; i < m; i += 256) {
        int v = staged[e0 + i];
        int dl = ((unsigned)v) >> 24;
        int s = v & 0xFFFFFF;
        int q = (s >= q2) ? ((s >= q3) ? 3 : 2) : ((s >= q1) ? 1 : 0);
        atomicAdd(&scnt[dl * 4 + q], 1);
    }
    __syncthreads();
    int c0 = scnt[t * 4 + 0], c1 = scnt[t * 4 + 1];
    int c2 = scnt[t * 4 + 2], c3 = scnt[t * 4 + 3];
    int tot = c0 + c1 + c2 + c3;
    swsum[t] = tot;
    __syncthreads();
    for (int off = 1; off < 256; off <<= 1) {   // Hillis-Steele inclusive over nodes
        int add = (t >= off) ? swsum[t - off] : 0;
        __syncthreads();
        swsum[t] += add;
        __syncthreads();
    }
    int excl = swsum[t] - tot;                  // node-exclusive prefix
    srel[t * 4 + 0] = excl;
    srel[t * 4 + 1] = excl + c0;
    srel[t * 4 + 2] = excl + c0 + c1;
    srel[t * 4 + 3] = excl + c0 + c1 + c2;
    if (t < nn) rp[n0 + t] = e0 + excl;
    if (b == NBKT - 1 && t == 0) rp[N] = E;
    __syncthreads();

    if (m <= SCOL_CAP) {
        for (int i = t; i < m; i += 256) {
            int v = staged[e0 + i];
            int dl = ((unsigned)v) >> 24;
            int s = v & 0xFFFFFF;
            int q = (s >= q2) ? ((s >= q3) ? 3 : 2) : ((s >= q1) ? 1 : 0);
            int p = srel[dl * 4 + q] + atomicAdd(&scur[dl * 4 + q], 1);
            scol[p] = s;
        }
        __syncthreads();
        for (int i = t; i < m; i += 256) col[e0 + i] = scol[i];
    } else {  // statistically unreachable overflow fallback
        for (int i = t; i < m; i += 256) {
            int v = staged[e0 + i];
            int dl = ((unsigned)v) >> 24;
            int s = v & 0xFFFFFF;
            int q = (s >= q2) ? ((s >= q3) ? 3 : 2) : ((s >= q1) ? 1 : 0);
            int p = srel[dl * 4 + q] + atomicAdd(&scur[dl * 4 + q], 1);
            col[e0 + p] = s;
        }
    }
}

// ---- Fused aggregate + MLP ---------------------------------------------
// Block = 256 threads = 32 nodes x 8 lanes; each lane handles 4 channels via
// uint2 (8B) loads => one gather instruction serves 8 edges (8 nodes/wave).
// col prefetched to LDS nontemporal; sv/st1 padded (33/17) for bank-freedom.
// NT stores emitted component-wise (builtin rejects HIP vector-type pointers).

template <bool RELU_OUT, bool OUT_BF16>
__global__ void agg_mlp(const ushort_t* __restrict__ xin, const int* __restrict__ rp,
                        const int* __restrict__ col,
                        const float* __restrict__ Wa, const float* __restrict__ ba,
                        const float* __restrict__ Wb, const float* __restrict__ bb,
                        void* __restrict__ outv, int N) {
    __shared__ float sWa[32 * 16];
    __shared__ float sWb[16 * 32];
    __shared__ float sba[16], sbb[32];
    __shared__ float sv[NPB * 33];
    __shared__ float st1[NPB * 17];
    __shared__ int scol[SCOL_N];

    int t = threadIdx.x;
    sWa[t] = Wa[t];  sWa[t + 256] = Wa[t + 256];
    sWb[t] = Wb[t];  sWb[t + 256] = Wb[t + 256];
    if (t < 16) sba[t] = ba[t];
    if (t < 32) sbb[t] = bb[t];

    int base = blockIdx.x * NPB;
    int kb = rp[base];
    int kt = rp[min(base + NPB, N)];
    int tot = kt - kb;
    bool ovf = (tot > SCOL_N);
    if (!ovf) {
        for (int i = t; i < tot; i += 256)
            scol[i] = __builtin_nontemporal_load(col + kb + i);
    }
    __syncthreads();

    int ln = t >> 3;          // node slot 0..31
    int sl = t & 7;           // channels 4*sl .. 4*sl+3
    int n  = base + ln;
    bool act = (n < N);
    const uint2* x2 = (const uint2*)xin;   // row = 8 uint2 (32 bf16)

    if (act) {
        uint2 us = x2[(size_t)n * 8 + sl];
        float v0 = bflo(us.x), v1 = bfhi(us.x), v2 = bflo(us.y), v3 = bfhi(us.y);
        int ks = rp[n], ke = rp[n + 1];
        if (!ovf) {
            int k = ks - kb, kend = ke - kb;
            for (; k + 8 <= kend; k += 8) {
                int s0 = scol[k + 0], s1 = scol[k + 1], s2 = scol[k + 2], s3 = scol[k + 3];
                int s4 = scol[k + 4], s5 = scol[k + 5], s6 = scol[k + 6], s7 = scol[k + 7];
                uint2 u0 = x2[(size_t)s0 * 8 + sl];
                uint2 u1 = x2[(size_t)s1 * 8 + sl];
                uint2 u2 = x2[(size_t)s2 * 8 + sl];
                uint2 u3 = x2[(size_t)s3 * 8 + sl];
                uint2 u4 = x2[(size_t)s4 * 8 + sl];
                uint2 u5 = x2[(size_t)s5 * 8 + sl];
                uint2 u6 = x2[(size_t)s6 * 8 + sl];
                uint2 u7 = x2[(size_t)s7 * 8 + sl];
                v0 += ((bflo(u0.x) + bflo(u1.x)) + (bflo(u2.x) + bflo(u3.x)))
                    + ((bflo(u4.x) + bflo(u5.x)) + (bflo(u6.x) + bflo(u7.x)));
                v1 += ((bfhi(u0.x) + bfhi(u1.x)) + (bfhi(u2.x) + bfhi(u3.x)))
                    + ((bfhi(u4.x) + bfhi(u5.x)) + (bfhi(u6.x) + bfhi(u7.x)));
                v2 += ((bflo(u0.y) + bflo(u1.y)) + (bflo(u2.y) + bflo(u3.y)))
                    + ((bflo(u4.y) + bflo(u5.y)) + (bflo(u6.y) + bflo(u7.y)));
                v3 += ((bfhi(u0.y) + bfhi(u1.y)) + (bfhi(u2.y) + bfhi(u3.y)))
                    + ((bfhi(u4.y) + bfhi(u5.y)) + (bfhi(u6.y) + bfhi(u7.y)));
            }
            for (; k < kend; ++k) {
                uint2 u = x2[(size_t)scol[k] * 8 + sl];
                v0 += bflo(u.x); v1 += bfhi(u.x); v2 += bflo(u.y); v3 += bfhi(u.y);
            }
        } else {  // statistically unreachable
            for (int k = ks; k < ke; ++k) {
                uint2 u = x2[(size_t)col[k] * 8 + sl];
                v0 += bflo(u.x); v1 += bfhi(u.x); v2 += bflo(u.y); v3 += bfhi(u.y);
            }
        }
        int c0 = sl * 4;
        sv[ln * 33 + c0 + 0] = v0; sv[ln * 33 + c0 + 1] = v1;
        sv[ln * 33 + c0 + 2] = v2; sv[ln * 33 + c0 + 3] = v3;
    }
    __syncthreads();

    if (act) {   // hidden units sl and sl+8 for node ln
        float ha = sba[sl], hb = sba[sl + 8];
        #pragma unroll
        for (int cc = 0; cc < 32; ++cc) {
            float vc = sv[ln * 33 + cc];
            ha += vc * sWa[cc * 16 + sl];
            hb += vc * sWa[cc * 16 + sl + 8];
        }
        st1[ln * 17 + sl]     = fmaxf(ha, 0.f);
        st1[ln * 17 + sl + 8] = fmaxf(hb, 0.f);
    }
    __syncthreads();

    if (act) {   // out channels 4*sl .. 4*sl+3 for node ln
        int c0 = sl * 4;
        float a0 = sbb[c0], a1 = sbb[c0 + 1], a2 = sbb[c0 + 2], a3 = sbb[c0 + 3];
        #pragma unroll
        for (int j = 0; j < 16; ++j) {
            float hj = st1[ln * 17 + j];
            a0 += hj * sWb[j * 32 + c0];
            a1 += hj * sWb[j * 32 + c0 + 1];
            a2 += hj * sWb[j * 32 + c0 + 2];
            a3 += hj * sWb[j * 32 + c0 + 3];
        }
        if (RELU_OUT) {
            a0 = fmaxf(a0, 0.f); a1 = fmaxf(a1, 0.f);
            a2 = fmaxf(a2, 0.f); a3 = fmaxf(a3, 0.f);
        }
        if (OUT_BF16) {
            uint_t p0 = (uint_t)f2bf(a0) | ((uint_t)f2bf(a1) << 16);
            uint_t p1 = (uint_t)f2bf(a2) | ((uint_t)f2bf(a3) << 16);
            uint_t* o = (uint_t*)outv + (size_t)n * 16 + sl * 2;
            __builtin_nontemporal_store(p0, o);
            __builtin_nontemporal_store(p1, o + 1);
        } else {
            float* o = (float*)outv + (size_t)n * 32 + c0;
            __builtin_nontemporal_store(a0, o);
            __builtin_nontemporal_store(a1, o + 1);
            __builtin_nontemporal_store(a2, o + 2);
            __builtin_nontemporal_store(a3, o + 3);
        }
    }
}

// ---- Launch -------------------------------------------------------------

extern "C" void kernel_launch(void* const* d_in, const int* in_sizes, int n_in,
                              void* d_out, int out_size, void* d_ws, size_t ws_size,
                              hipStream_t stream) {
    const float* x  = (const float*)d_in[0];
    const int*   ei = (const int*)d_in[1];
    const float* W1 = (const float*)d_in[2];
    const float* b1 = (const float*)d_in[3];
    const float* W2 = (const float*)d_in[4];
    const float* b2 = (const float*)d_in[5];
    const float* W3 = (const float*)d_in[6];
    const float* b3 = (const float*)d_in[7];
    const float* W4 = (const float*)d_in[8];
    const float* b4 = (const float*)d_in[9];

    const int N = in_sizes[0] / 32;
    const int E = in_sizes[1] / 2;
    const int* src = ei;
    const int* dst = ei + E;

    const int NBKT = (N + BKT_NODES - 1) >> BKT_SHIFT;   // 391
    const int NBLK = (E + EPB - 1) / EPB;                // 306

    char* ws = (char*)d_ws;
    size_t o = 0;
    auto alloc = [&](size_t bytes) -> char* {
        o = (o + 255) & ~(size_t)255;
        char* r = ws + o;
        o += bytes;
        return r;
    };
    int*      hist   = (int*)     alloc(4 * (size_t)NBLK * NBKT);
    int*      T      = (int*)     alloc(4 * (size_t)NBKT);
    int*      Tscan  = (int*)     alloc(4 * (size_t)(NBKT + 1));
    int*      staged = (int*)     alloc(4 * (size_t)E);
    int*      rp     = (int*)     alloc(4 * (size_t)(N + 1));
    int*      col    = (int*)     alloc(4 * (size_t)E);
    ushort_t* xb     = (ushort_t*)alloc(2 * (size_t)N * 32);
    ushort_t* hb     = (ushort_t*)alloc(2 * (size_t)N * 32);

    int n4 = N * 32 / 4;
    to_bf16<<<(n4 + 255) / 256, 256, 0, stream>>>((const float4*)x, xb, n4);

    histA<<<NBLK, 512, 0, stream>>>(dst, hist, E, NBKT);
    colscan<<<NBKT, 256, 0, stream>>>(hist, T, NBLK, NBKT);
    scan_small<<<1, 1024, 0, stream>>>(T, Tscan, NBKT, E);
    scatter_kernel<<<NBLK, 512, 0, stream>>>(src, dst, hist, Tscan, staged, E, NBKT);
    int q1 = N / 4, q2 = N / 2, q3 = (3 * N) / 4;
    fine_fill<<<NBKT, 256, 0, stream>>>(staged, Tscan, rp, col, N, E, NBKT, q1, q2, q3);

    agg_mlp<true,  true ><<<(N + NPB - 1) / NPB, 256, 0, stream>>>(xb, rp, col,
                                                                   W1, b1, W2, b2, hb, N);
    agg_mlp<false, false><<<(N + NPB - 1) / NPB, 256, 0, stream>>>(hb, rp, col,
                                                                   W3, b3, W4, b4, d_out, N);
}